// Round 1
// baseline (234.294 us; speedup 1.0000x reference)
//
#include <hip/hip_runtime.h>
#include <hip/hip_bf16.h>
#include <cstddef>
#include <cstdint>

typedef __bf16 bf16_t;
typedef __attribute__((ext_vector_type(8))) __bf16 bf16x8;
typedef __attribute__((ext_vector_type(4))) float f32x4;

#define B_   4
#define T_   2048
#define D_   512
#define H_   8
#define HD_  64
#define BT_  8192
#define N3_  1536

__device__ inline f32x4 mfma16(bf16x8 a, bf16x8 b, f32x4 c) {
  return __builtin_amdgcn_mfma_f32_16x16x32_bf16(a, b, c, 0, 0, 0);
}

__device__ inline float rmax16(float v) {
  v = fmaxf(v, __shfl_xor(v, 1));
  v = fmaxf(v, __shfl_xor(v, 2));
  v = fmaxf(v, __shfl_xor(v, 4));
  v = fmaxf(v, __shfl_xor(v, 8));
  return v;
}
__device__ inline float rsum16(float v) {
  v += __shfl_xor(v, 1);
  v += __shfl_xor(v, 2);
  v += __shfl_xor(v, 4);
  v += __shfl_xor(v, 8);
  return v;
}

// ---------------- transpose + cast fp32 [R][C] -> bf16 [C][R] ----------------
__global__ __launch_bounds__(256) void k_tcast(const float* __restrict__ in,
                                               bf16_t* __restrict__ out,
                                               int R, int C) {
  __shared__ bf16_t tile[64][72];
  const int c0 = blockIdx.x * 64, r0 = blockIdx.y * 64;
  const int t = threadIdx.x;
  const int rr = t >> 4;         // 0..15
  const int cc = (t & 15) * 4;   // 0..60
#pragma unroll
  for (int p = 0; p < 4; ++p) {
    int r = p * 16 + rr;
    f32x4 v = *reinterpret_cast<const f32x4*>(&in[(size_t)(r0 + r) * C + c0 + cc]);
#pragma unroll
    for (int i = 0; i < 4; ++i) tile[cc + i][r] = (bf16_t)v[i];
  }
  __syncthreads();
#pragma unroll
  for (int p = 0; p < 4; ++p) {
    int c = p * 16 + rr;
    union { uint2 u; bf16_t e[4]; } pk;
#pragma unroll
    for (int i = 0; i < 4; ++i) pk.e[i] = tile[c][cc + i];
    *reinterpret_cast<uint2*>(&out[(size_t)(c0 + c) * R + r0 + cc]) = pk.u;
  }
}

// ---------------- bf16 transpose: V [bh][2048][64] -> Vt [bh][64][2048] -----
__global__ __launch_bounds__(256) void k_vtrans(const bf16_t* __restrict__ V,
                                                bf16_t* __restrict__ Vt) {
  __shared__ bf16_t tile[64][72];
  const int bh = blockIdx.y;
  const int t0 = blockIdx.x * 64;
  const bf16_t* src = V + (size_t)bh * T_ * HD_ + (size_t)t0 * HD_;
  bf16_t* dst = Vt + (size_t)bh * HD_ * T_ + t0;
  const int tid = threadIdx.x;
  const int r2 = tid >> 3;         // 0..31
  const int c8 = (tid & 7) * 8;    // 0..56
#pragma unroll
  for (int p = 0; p < 2; ++p) {
    int r = p * 32 + r2;
    bf16x8 v = *reinterpret_cast<const bf16x8*>(&src[r * HD_ + c8]);
#pragma unroll
    for (int i = 0; i < 8; ++i) tile[c8 + i][r] = v[i];
  }
  __syncthreads();
#pragma unroll
  for (int p = 0; p < 2; ++p) {
    int d = p * 32 + r2;
    bf16x8 v;
#pragma unroll
    for (int i = 0; i < 8; ++i) v[i] = tile[d][c8 + i];
    *reinterpret_cast<bf16x8*>(&dst[(size_t)d * T_ + c8]) = v;
  }
}

// ---------------- GEMM1: qkv = x @ Wqkv + b -> Q,K,V bf16 [bh][t][d] --------
__global__ __launch_bounds__(256) void k_gemm_qkv(
    const float* __restrict__ X, const bf16_t* __restrict__ Wt,
    const float* __restrict__ bias, bf16_t* __restrict__ Q,
    bf16_t* __restrict__ K, bf16_t* __restrict__ V) {
  __shared__ bf16_t As[128][40];
  __shared__ bf16_t Bs[128][40];
  const int bm0 = blockIdx.x * 128, bn0 = blockIdx.y * 128;
  const int tid = threadIdx.x, lane = tid & 63, wid = tid >> 6;
  const int wm = wid >> 1, wn = wid & 1;
  const int srow = tid >> 1, sh = (tid & 1) * 16;
  f32x4 acc[4][4] = {};
  for (int kt = 0; kt < D_; kt += 32) {
    {  // stage A (fp32 -> bf16)
      const float* s = &X[(size_t)(bm0 + srow) * D_ + kt + sh];
      f32x4 v0 = *reinterpret_cast<const f32x4*>(s);
      f32x4 v1 = *reinterpret_cast<const f32x4*>(s + 4);
      f32x4 v2 = *reinterpret_cast<const f32x4*>(s + 8);
      f32x4 v3 = *reinterpret_cast<const f32x4*>(s + 12);
      bf16x8 lo, hi;
#pragma unroll
      for (int i = 0; i < 4; ++i) {
        lo[i] = (bf16_t)v0[i]; lo[4 + i] = (bf16_t)v1[i];
        hi[i] = (bf16_t)v2[i]; hi[4 + i] = (bf16_t)v3[i];
      }
      *reinterpret_cast<bf16x8*>(&As[srow][sh]) = lo;
      *reinterpret_cast<bf16x8*>(&As[srow][sh + 8]) = hi;
    }
    {  // stage B (already bf16, [N][K])
      const bf16_t* s = &Wt[(size_t)(bn0 + srow) * D_ + kt + sh];
      *reinterpret_cast<bf16x8*>(&Bs[srow][sh]) =
          *reinterpret_cast<const bf16x8*>(s);
      *reinterpret_cast<bf16x8*>(&Bs[srow][sh + 8]) =
          *reinterpret_cast<const bf16x8*>(s + 8);
    }
    __syncthreads();
    const int fr = lane & 15, kq = (lane >> 4) * 8;
    bf16x8 af[4], bfr[4];
#pragma unroll
    for (int m = 0; m < 4; ++m)
      af[m] = *reinterpret_cast<const bf16x8*>(&As[wm * 64 + m * 16 + fr][kq]);
#pragma unroll
    for (int n = 0; n < 4; ++n)
      bfr[n] = *reinterpret_cast<const bf16x8*>(&Bs[wn * 64 + n * 16 + fr][kq]);
#pragma unroll
    for (int m = 0; m < 4; ++m)
#pragma unroll
      for (int n = 0; n < 4; ++n)
        acc[m][n] = mfma16(af[m], bfr[n], acc[m][n]);
    __syncthreads();
  }
  // epilogue: +bias, cast bf16, scatter to Q/K/V [b][h][t][d]
  const int fr = lane & 15, fq = lane >> 4;
#pragma unroll
  for (int n = 0; n < 4; ++n) {
    int ng = bn0 + wn * 64 + n * 16 + fr;
    float bv = bias[ng];
    int sec = ng >> 9, ns = ng & 511;
    int h = ns >> 6, d = ns & 63;
    bf16_t* dst = sec == 0 ? Q : (sec == 1 ? K : V);
#pragma unroll
    for (int m = 0; m < 4; ++m) {
      int mg = bm0 + wm * 64 + m * 16 + fq * 4;
#pragma unroll
      for (int j = 0; j < 4; ++j) {
        int row = mg + j;
        int bb = row >> 11, tt = row & 2047;
        dst[(((size_t)(bb * H_ + h)) * T_ + tt) * HD_ + d] =
            (bf16_t)(acc[m][n][j] + bv);
      }
    }
  }
}

// ---------------- GEMM2: out = ctx @ Wfc + b (fp32 out) ---------------------
__global__ __launch_bounds__(256) void k_gemm_fc(
    const bf16_t* __restrict__ A, const bf16_t* __restrict__ Wt,
    const float* __restrict__ bias, float* __restrict__ Out) {
  __shared__ bf16_t As[128][40];
  __shared__ bf16_t Bs[128][40];
  const int bm0 = blockIdx.x * 128, bn0 = blockIdx.y * 128;
  const int tid = threadIdx.x, lane = tid & 63, wid = tid >> 6;
  const int wm = wid >> 1, wn = wid & 1;
  const int srow = tid >> 1, sh = (tid & 1) * 16;
  f32x4 acc[4][4] = {};
  for (int kt = 0; kt < D_; kt += 32) {
    {
      const bf16_t* s = &A[(size_t)(bm0 + srow) * D_ + kt + sh];
      *reinterpret_cast<bf16x8*>(&As[srow][sh]) =
          *reinterpret_cast<const bf16x8*>(s);
      *reinterpret_cast<bf16x8*>(&As[srow][sh + 8]) =
          *reinterpret_cast<const bf16x8*>(s + 8);
    }
    {
      const bf16_t* s = &Wt[(size_t)(bn0 + srow) * D_ + kt + sh];
      *reinterpret_cast<bf16x8*>(&Bs[srow][sh]) =
          *reinterpret_cast<const bf16x8*>(s);
      *reinterpret_cast<bf16x8*>(&Bs[srow][sh + 8]) =
          *reinterpret_cast<const bf16x8*>(s + 8);
    }
    __syncthreads();
    const int fr = lane & 15, kq = (lane >> 4) * 8;
    bf16x8 af[4], bfr[4];
#pragma unroll
    for (int m = 0; m < 4; ++m)
      af[m] = *reinterpret_cast<const bf16x8*>(&As[wm * 64 + m * 16 + fr][kq]);
#pragma unroll
    for (int n = 0; n < 4; ++n)
      bfr[n] = *reinterpret_cast<const bf16x8*>(&Bs[wn * 64 + n * 16 + fr][kq]);
#pragma unroll
    for (int m = 0; m < 4; ++m)
#pragma unroll
      for (int n = 0; n < 4; ++n)
        acc[m][n] = mfma16(af[m], bfr[n], acc[m][n]);
    __syncthreads();
  }
  const int fr = lane & 15, fq = lane >> 4;
#pragma unroll
  for (int n = 0; n < 4; ++n) {
    int ng = bn0 + wn * 64 + n * 16 + fr;
    float bv = bias[ng];
#pragma unroll
    for (int m = 0; m < 4; ++m) {
      int mg = bm0 + wm * 64 + m * 16 + fq * 4;
#pragma unroll
      for (int j = 0; j < 4; ++j)
        Out[(size_t)(mg + j) * D_ + ng] = acc[m][n][j] + bv;
    }
  }
}

// ---------------- flash attention: Q,K [bh][t][d], Vt [bh][d][t] ------------
__global__ __launch_bounds__(256) void k_attn(
    const bf16_t* __restrict__ Q, const bf16_t* __restrict__ K,
    const bf16_t* __restrict__ Vt, bf16_t* __restrict__ Ctx) {
  __shared__ bf16_t Ks[64 * 64];     // row = kv t-local (128B), XOR-swizzled
  __shared__ bf16_t Vs[64 * 64];     // row = d (128B), XOR-swizzled
  __shared__ bf16_t Ps[4][32 * 64];  // per-wave P, row = q-local, swizzled
  const int bh = blockIdx.y;
  const int q0 = blockIdx.x * 128;
  const int tid = threadIdx.x, lane = tid & 63, wid = tid >> 6;
  const int fr = lane & 15, fq = lane >> 4;
  const bf16_t* Qp = Q + (size_t)bh * T_ * HD_;
  const bf16_t* Kp = K + (size_t)bh * T_ * HD_;
  const bf16_t* Vp = Vt + (size_t)bh * HD_ * T_;
  bf16x8 qf[2][2];
#pragma unroll
  for (int mb = 0; mb < 2; ++mb)
#pragma unroll
    for (int ks = 0; ks < 2; ++ks)
      qf[mb][ks] = *reinterpret_cast<const bf16x8*>(
          &Qp[(size_t)(q0 + wid * 32 + mb * 16 + fr) * HD_ + ks * 32 + fq * 8]);
  f32x4 oacc[2][4] = {};
  float mrow[2][4], lrow[2][4];
#pragma unroll
  for (int mb = 0; mb < 2; ++mb)
#pragma unroll
    for (int j = 0; j < 4; ++j) { mrow[mb][j] = -1e30f; lrow[mb][j] = 0.f; }
  const float c1 = 0.125f * 1.44269504089f;  // scale * log2(e)
  const int srow = tid >> 2;         // 0..63
  const int schb = (tid & 3) * 16;   // byte chunk 0,16,32,48
  for (int kt = 0; kt < T_; kt += 64) {
    {  // stage K tile [t-local][d] and Vt tile [d][t-local], swizzled
      const int xb = (srow & 7) << 4;
      bf16x8 a = *reinterpret_cast<const bf16x8*>(
          &Kp[(size_t)(kt + srow) * HD_ + (schb >> 1)]);
      bf16x8 b = *reinterpret_cast<const bf16x8*>(
          &Kp[(size_t)(kt + srow) * HD_ + (schb >> 1) + 32]);
      char* kb = reinterpret_cast<char*>(Ks) + srow * 128;
      *reinterpret_cast<bf16x8*>(kb + (schb ^ xb)) = a;
      *reinterpret_cast<bf16x8*>(kb + ((schb + 64) ^ xb)) = b;
      bf16x8 c = *reinterpret_cast<const bf16x8*>(
          &Vp[(size_t)srow * T_ + kt + (schb >> 1)]);
      bf16x8 d = *reinterpret_cast<const bf16x8*>(
          &Vp[(size_t)srow * T_ + kt + (schb >> 1) + 32]);
      char* vb = reinterpret_cast<char*>(Vs) + srow * 128;
      *reinterpret_cast<bf16x8*>(vb + (schb ^ xb)) = c;
      *reinterpret_cast<bf16x8*>(vb + ((schb + 64) ^ xb)) = d;
    }
    __syncthreads();
    // QK^T
    f32x4 sacc[2][4] = {};
    bf16x8 kf[4][2];
#pragma unroll
    for (int nb = 0; nb < 4; ++nb) {
      int trow = nb * 16 + fr;
      int xr = (trow & 7) << 4;
#pragma unroll
      for (int ks = 0; ks < 2; ++ks)
        kf[nb][ks] = *reinterpret_cast<const bf16x8*>(
            reinterpret_cast<char*>(Ks) + trow * 128 + ((ks * 64 + fq * 16) ^ xr));
    }
#pragma unroll
    for (int ks = 0; ks < 2; ++ks)
#pragma unroll
      for (int mb = 0; mb < 2; ++mb)
#pragma unroll
        for (int nb = 0; nb < 4; ++nb)
          sacc[mb][nb] = mfma16(qf[mb][ks], kf[nb][ks], sacc[mb][nb]);
    // online softmax
#pragma unroll
    for (int mb = 0; mb < 2; ++mb) {
      float tm[4];
#pragma unroll
      for (int j = 0; j < 4; ++j) {
        float v = fmaxf(fmaxf(sacc[mb][0][j], sacc[mb][1][j]),
                        fmaxf(sacc[mb][2][j], sacc[mb][3][j]));
        tm[j] = rmax16(v);
      }
      float p[4][4];
#pragma unroll
      for (int j = 0; j < 4; ++j) {
        float mn = fmaxf(mrow[mb][j], tm[j]);
        float sc = __builtin_exp2f((mrow[mb][j] - mn) * c1);
        mrow[mb][j] = mn;
        float rs = 0.f;
#pragma unroll
        for (int nb = 0; nb < 4; ++nb) {
          float pv = __builtin_exp2f((sacc[mb][nb][j] - mn) * c1);
          p[nb][j] = pv;
          rs += pv;
        }
        rs = rsum16(rs);
        lrow[mb][j] = lrow[mb][j] * sc + rs;
#pragma unroll
        for (int nb = 0; nb < 4; ++nb) oacc[mb][nb][j] *= sc;
      }
      char* pbase = reinterpret_cast<char*>(Ps[wid]);
#pragma unroll
      for (int j = 0; j < 4; ++j) {
        int prow = mb * 16 + fq * 4 + j;
        int xr = (prow & 7) << 4;
#pragma unroll
        for (int nb = 0; nb < 4; ++nb) {
          int cb = (nb * 16 + fr) * 2;
          *reinterpret_cast<bf16_t*>(pbase + prow * 128 + (cb ^ xr)) =
              (bf16_t)p[nb][j];
        }
      }
    }
    asm volatile("s_waitcnt lgkmcnt(0)" ::: "memory");
    {  // PV
      char* pbase = reinterpret_cast<char*>(Ps[wid]);
      bf16x8 pa[2][2], vf[4][2];
#pragma unroll
      for (int mb = 0; mb < 2; ++mb) {
        int prow = mb * 16 + fr;
        int xr = (prow & 7) << 4;
#pragma unroll
        for (int ks = 0; ks < 2; ++ks)
          pa[mb][ks] = *reinterpret_cast<const bf16x8*>(
              pbase + prow * 128 + ((ks * 64 + fq * 16) ^ xr));
      }
#pragma unroll
      for (int nb = 0; nb < 4; ++nb) {
        int drow = nb * 16 + fr;
        int xr = (drow & 7) << 4;
#pragma unroll
        for (int ks = 0; ks < 2; ++ks)
          vf[nb][ks] = *reinterpret_cast<const bf16x8*>(
              reinterpret_cast<char*>(Vs) + drow * 128 + ((ks * 64 + fq * 16) ^ xr));
      }
#pragma unroll
      for (int ks = 0; ks < 2; ++ks)
#pragma unroll
        for (int mb = 0; mb < 2; ++mb)
#pragma unroll
          for (int nb = 0; nb < 4; ++nb)
            oacc[mb][nb] = mfma16(pa[mb][ks], vf[nb][ks], oacc[mb][nb]);
    }
    __syncthreads();
  }
  // epilogue: ctx[b][t][h*64+d] bf16
  const int bb = bh >> 3, hh = bh & 7;
#pragma unroll
  for (int mb = 0; mb < 2; ++mb)
#pragma unroll
    for (int nb = 0; nb < 4; ++nb)
#pragma unroll
      for (int j = 0; j < 4; ++j) {
        int trow = q0 + wid * 32 + mb * 16 + fq * 4 + j;
        float val = oacc[mb][nb][j] / lrow[mb][j];
        Ctx[((size_t)(bb * T_ + trow)) * D_ + hh * HD_ + nb * 16 + fr] =
            (bf16_t)val;
      }
}

extern "C" void kernel_launch(void* const* d_in, const int* in_sizes, int n_in,
                              void* d_out, int out_size, void* d_ws,
                              size_t ws_size, hipStream_t stream) {
  const float* x    = (const float*)d_in[0];
  const float* Wqkv = (const float*)d_in[1];
  const float* bqkv = (const float*)d_in[2];
  const float* Wfc  = (const float*)d_in[3];
  const float* bfc  = (const float*)d_in[4];
  float* out = (float*)d_out;

  char* ws = (char*)d_ws;
  size_t off = 0;
  bf16_t* Wqt = (bf16_t*)(ws + off); off += (size_t)N3_ * D_ * 2;   // 1.5 MB
  bf16_t* Wft = (bf16_t*)(ws + off); off += (size_t)D_ * D_ * 2;    // 0.5 MB
  bf16_t* Qb  = (bf16_t*)(ws + off); off += (size_t)BT_ * D_ * 2;   // 8.4 MB
  bf16_t* Kb  = (bf16_t*)(ws + off); off += (size_t)BT_ * D_ * 2;
  bf16_t* Vb  = (bf16_t*)(ws + off); off += (size_t)BT_ * D_ * 2;
  bf16_t* Vtb = (bf16_t*)(ws + off); off += (size_t)BT_ * D_ * 2;
  bf16_t* Ctx = Vb;  // V is dead after k_vtrans; reuse for ctx

  k_tcast<<<dim3(N3_ / 64, D_ / 64), 256, 0, stream>>>(Wqkv, Wqt, D_, N3_);
  k_tcast<<<dim3(D_ / 64, D_ / 64), 256, 0, stream>>>(Wfc, Wft, D_, D_);
  k_gemm_qkv<<<dim3(BT_ / 128, N3_ / 128), 256, 0, stream>>>(x, Wqt, bqkv, Qb,
                                                             Kb, Vb);
  k_vtrans<<<dim3(T_ / 64, B_ * H_), 256, 0, stream>>>(Vb, Vtb);
  k_attn<<<dim3(T_ / 128, B_ * H_), 256, 0, stream>>>(Qb, Kb, Vtb, Ctx);
  k_gemm_fc<<<dim3(BT_ / 128, D_ / 128), 256, 0, stream>>>(Ctx, Wft, bfc, out);
}

// Round 2
// 175.906 us; speedup vs baseline: 1.3319x; 1.3319x over previous
//
#include <hip/hip_runtime.h>
#include <hip/hip_bf16.h>
#include <cstddef>
#include <cstdint>

typedef __bf16 bf16_t;
typedef __attribute__((ext_vector_type(8))) __bf16 bf16x8;
typedef __attribute__((ext_vector_type(4))) float f32x4;
typedef __attribute__((ext_vector_type(16))) float f32x16;

#define B_   4
#define T_   2048
#define D_   512
#define H_   8
#define HD_  64
#define BT_  8192
#define N3_  1536

__device__ inline f32x4 mfma16(bf16x8 a, bf16x8 b, f32x4 c) {
  return __builtin_amdgcn_mfma_f32_16x16x32_bf16(a, b, c, 0, 0, 0);
}
__device__ inline f32x16 mfma32(bf16x8 a, bf16x8 b, f32x16 c) {
  return __builtin_amdgcn_mfma_f32_32x32x16_bf16(a, b, c, 0, 0, 0);
}

// ---------------- transpose + cast fp32 [R][C] -> bf16 [C][R] ----------------
__global__ __launch_bounds__(256) void k_tcast(const float* __restrict__ in,
                                               bf16_t* __restrict__ out,
                                               int R, int C) {
  __shared__ bf16_t tile[64][72];
  const int c0 = blockIdx.x * 64, r0 = blockIdx.y * 64;
  const int t = threadIdx.x;
  const int rr = t >> 4;         // 0..15
  const int cc = (t & 15) * 4;   // 0..60
#pragma unroll
  for (int p = 0; p < 4; ++p) {
    int r = p * 16 + rr;
    f32x4 v = *reinterpret_cast<const f32x4*>(&in[(size_t)(r0 + r) * C + c0 + cc]);
#pragma unroll
    for (int i = 0; i < 4; ++i) tile[cc + i][r] = (bf16_t)v[i];
  }
  __syncthreads();
#pragma unroll
  for (int p = 0; p < 4; ++p) {
    int c = p * 16 + rr;
    union { uint2 u; bf16_t e[4]; } pk;
#pragma unroll
    for (int i = 0; i < 4; ++i) pk.e[i] = tile[c][cc + i];
    *reinterpret_cast<uint2*>(&out[(size_t)(c0 + c) * R + r0 + cc]) = pk.u;
  }
}

// ---------------- bf16 transpose: V [bh][2048][64] -> Vt [bh][64][2048] -----
__global__ __launch_bounds__(256) void k_vtrans(const bf16_t* __restrict__ V,
                                                bf16_t* __restrict__ Vt) {
  __shared__ bf16_t tile[64][72];
  const int bh = blockIdx.y;
  const int t0 = blockIdx.x * 64;
  const bf16_t* src = V + (size_t)bh * T_ * HD_ + (size_t)t0 * HD_;
  bf16_t* dst = Vt + (size_t)bh * HD_ * T_ + t0;
  const int tid = threadIdx.x;
  const int r2 = tid >> 3;         // 0..31
  const int c8 = (tid & 7) * 8;    // 0..56
#pragma unroll
  for (int p = 0; p < 2; ++p) {
    int r = p * 32 + r2;
    bf16x8 v = *reinterpret_cast<const bf16x8*>(&src[r * HD_ + c8]);
#pragma unroll
    for (int i = 0; i < 8; ++i) tile[c8 + i][r] = v[i];
  }
  __syncthreads();
#pragma unroll
  for (int p = 0; p < 2; ++p) {
    int d = p * 32 + r2;
    bf16x8 v;
#pragma unroll
    for (int i = 0; i < 8; ++i) v[i] = tile[d][c8 + i];
    *reinterpret_cast<bf16x8*>(&dst[(size_t)d * T_ + c8]) = v;
  }
}

// ---------------- GEMM1: qkv = x @ Wqkv + b -> Q,K,V bf16 [bh][t][d] --------
__global__ __launch_bounds__(256) void k_gemm_qkv(
    const float* __restrict__ X, const bf16_t* __restrict__ Wt,
    const float* __restrict__ bias, bf16_t* __restrict__ Q,
    bf16_t* __restrict__ K, bf16_t* __restrict__ V) {
  __shared__ bf16_t As[128][40];
  __shared__ bf16_t Bs[128][40];
  const int bm0 = blockIdx.x * 128, bn0 = blockIdx.y * 128;
  const int tid = threadIdx.x, lane = tid & 63, wid = tid >> 6;
  const int wm = wid >> 1, wn = wid & 1;
  const int srow = tid >> 1, sh = (tid & 1) * 16;
  f32x4 acc[4][4] = {};
  for (int kt = 0; kt < D_; kt += 32) {
    {  // stage A (fp32 -> bf16)
      const float* s = &X[(size_t)(bm0 + srow) * D_ + kt + sh];
      f32x4 v0 = *reinterpret_cast<const f32x4*>(s);
      f32x4 v1 = *reinterpret_cast<const f32x4*>(s + 4);
      f32x4 v2 = *reinterpret_cast<const f32x4*>(s + 8);
      f32x4 v3 = *reinterpret_cast<const f32x4*>(s + 12);
      bf16x8 lo, hi;
#pragma unroll
      for (int i = 0; i < 4; ++i) {
        lo[i] = (bf16_t)v0[i]; lo[4 + i] = (bf16_t)v1[i];
        hi[i] = (bf16_t)v2[i]; hi[4 + i] = (bf16_t)v3[i];
      }
      *reinterpret_cast<bf16x8*>(&As[srow][sh]) = lo;
      *reinterpret_cast<bf16x8*>(&As[srow][sh + 8]) = hi;
    }
    {  // stage B (already bf16, [N][K])
      const bf16_t* s = &Wt[(size_t)(bn0 + srow) * D_ + kt + sh];
      *reinterpret_cast<bf16x8*>(&Bs[srow][sh]) =
          *reinterpret_cast<const bf16x8*>(s);
      *reinterpret_cast<bf16x8*>(&Bs[srow][sh + 8]) =
          *reinterpret_cast<const bf16x8*>(s + 8);
    }
    __syncthreads();
    const int fr = lane & 15, kq = (lane >> 4) * 8;
    bf16x8 af[4], bfr[4];
#pragma unroll
    for (int m = 0; m < 4; ++m)
      af[m] = *reinterpret_cast<const bf16x8*>(&As[wm * 64 + m * 16 + fr][kq]);
#pragma unroll
    for (int n = 0; n < 4; ++n)
      bfr[n] = *reinterpret_cast<const bf16x8*>(&Bs[wn * 64 + n * 16 + fr][kq]);
#pragma unroll
    for (int m = 0; m < 4; ++m)
#pragma unroll
      for (int n = 0; n < 4; ++n)
        acc[m][n] = mfma16(af[m], bfr[n], acc[m][n]);
    __syncthreads();
  }
  // epilogue: +bias, cast bf16, scatter to Q/K/V [b][h][t][d]
  const int fr = lane & 15, fq = lane >> 4;
#pragma unroll
  for (int n = 0; n < 4; ++n) {
    int ng = bn0 + wn * 64 + n * 16 + fr;
    float bv = bias[ng];
    int sec = ng >> 9, ns = ng & 511;
    int h = ns >> 6, d = ns & 63;
    bf16_t* dst = sec == 0 ? Q : (sec == 1 ? K : V);
#pragma unroll
    for (int m = 0; m < 4; ++m) {
      int mg = bm0 + wm * 64 + m * 16 + fq * 4;
#pragma unroll
      for (int j = 0; j < 4; ++j) {
        int row = mg + j;
        int bb = row >> 11, tt = row & 2047;
        dst[(((size_t)(bb * H_ + h)) * T_ + tt) * HD_ + d] =
            (bf16_t)(acc[m][n][j] + bv);
      }
    }
  }
}

// ---------------- GEMM2: out = ctx @ Wfc + b (fp32 out) ---------------------
__global__ __launch_bounds__(256) void k_gemm_fc(
    const bf16_t* __restrict__ A, const bf16_t* __restrict__ Wt,
    const float* __restrict__ bias, float* __restrict__ Out) {
  __shared__ bf16_t As[128][40];
  __shared__ bf16_t Bs[128][40];
  const int bm0 = blockIdx.x * 128, bn0 = blockIdx.y * 128;
  const int tid = threadIdx.x, lane = tid & 63, wid = tid >> 6;
  const int wm = wid >> 1, wn = wid & 1;
  const int srow = tid >> 1, sh = (tid & 1) * 16;
  f32x4 acc[4][4] = {};
  for (int kt = 0; kt < D_; kt += 32) {
    {
      const bf16_t* s = &A[(size_t)(bm0 + srow) * D_ + kt + sh];
      *reinterpret_cast<bf16x8*>(&As[srow][sh]) =
          *reinterpret_cast<const bf16x8*>(s);
      *reinterpret_cast<bf16x8*>(&As[srow][sh + 8]) =
          *reinterpret_cast<const bf16x8*>(s + 8);
    }
    {
      const bf16_t* s = &Wt[(size_t)(bn0 + srow) * D_ + kt + sh];
      *reinterpret_cast<bf16x8*>(&Bs[srow][sh]) =
          *reinterpret_cast<const bf16x8*>(s);
      *reinterpret_cast<bf16x8*>(&Bs[srow][sh + 8]) =
          *reinterpret_cast<const bf16x8*>(s + 8);
    }
    __syncthreads();
    const int fr = lane & 15, kq = (lane >> 4) * 8;
    bf16x8 af[4], bfr[4];
#pragma unroll
    for (int m = 0; m < 4; ++m)
      af[m] = *reinterpret_cast<const bf16x8*>(&As[wm * 64 + m * 16 + fr][kq]);
#pragma unroll
    for (int n = 0; n < 4; ++n)
      bfr[n] = *reinterpret_cast<const bf16x8*>(&Bs[wn * 64 + n * 16 + fr][kq]);
#pragma unroll
    for (int m = 0; m < 4; ++m)
#pragma unroll
      for (int n = 0; n < 4; ++n)
        acc[m][n] = mfma16(af[m], bfr[n], acc[m][n]);
    __syncthreads();
  }
  const int fr = lane & 15, fq = lane >> 4;
#pragma unroll
  for (int n = 0; n < 4; ++n) {
    int ng = bn0 + wn * 64 + n * 16 + fr;
    float bv = bias[ng];
#pragma unroll
    for (int m = 0; m < 4; ++m) {
      int mg = bm0 + wm * 64 + m * 16 + fq * 4;
#pragma unroll
      for (int j = 0; j < 4; ++j)
        Out[(size_t)(mg + j) * D_ + ng] = acc[m][n][j] + bv;
    }
  }
}

// ---------------- attention tile: 32 q-rows (per wave) x 32 kv --------------
// Swapped QK^T: S^T = mfma(A=K, B=Q) -> lane owns q = lane&31 (cols), 16 k's
// in regs (k = (r&3)+8*(r>>2)+4*kh). Softmax fully in-register; P -> PV
// A-frag via bf16 pair packing + shfl_xor(32) half exchange.
__device__ __forceinline__ void attn_tile(
    int kt, const bf16_t* __restrict__ Kp, const bf16_t* __restrict__ Vp,
    const bf16x8 (&qf)[4], const bf16x8 (&kc)[4], bf16x8 (&kn)[4],
    f32x16& o0, f32x16& o1, float& ml, float& lsum, const int kh,
    const bool lolane) {
  // V B-frags for this tile: vf[dtile][kstep], each 16B contiguous from Vt row
  bf16x8 v00 = *reinterpret_cast<const bf16x8*>(Vp + kt);
  bf16x8 v01 = *reinterpret_cast<const bf16x8*>(Vp + kt + 16);
  bf16x8 v10 = *reinterpret_cast<const bf16x8*>(Vp + 32 * T_ + kt);
  bf16x8 v11 = *reinterpret_cast<const bf16x8*>(Vp + 32 * T_ + kt + 16);
  f32x16 s;
#pragma unroll
  for (int i = 0; i < 16; ++i) s[i] = 0.f;
  s = mfma32(kc[0], qf[0], s);
  s = mfma32(kc[1], qf[1], s);
  s = mfma32(kc[2], qf[2], s);
  s = mfma32(kc[3], qf[3], s);
  // prefetch next K tile into kn (hidden under softmax+PV)
  if (kt + 32 < T_) {
    const bf16_t* kp2 = Kp + (size_t)(kt + 32) * HD_;
    kn[0] = *reinterpret_cast<const bf16x8*>(kp2);
    kn[1] = *reinterpret_cast<const bf16x8*>(kp2 + 16);
    kn[2] = *reinterpret_cast<const bf16x8*>(kp2 + 32);
    kn[3] = *reinterpret_cast<const bf16x8*>(kp2 + 48);
  }
  const float c1 = 0.18033688011112042f;  // 0.125 * log2(e)
  float a = fmaxf(fmaxf(fmaxf(s[0], s[1]), fmaxf(s[2], s[3])),
                  fmaxf(fmaxf(s[4], s[5]), fmaxf(s[6], s[7])));
  float b = fmaxf(fmaxf(fmaxf(s[8], s[9]), fmaxf(s[10], s[11])),
                  fmaxf(fmaxf(s[12], s[13]), fmaxf(s[14], s[15])));
  float pmax = fmaxf(a, b);
  pmax = fmaxf(pmax, __shfl_xor(pmax, 32));
  float pml = pmax * c1;
  if (__any(pml > ml + 8.f)) {  // defer-max: rescale only on real growth
    float mln = fmaxf(ml, pml);
    float sc = __builtin_exp2f(ml - mln);
    ml = mln;
    lsum *= sc;
#pragma unroll
    for (int r = 0; r < 16; ++r) {
      const int qr = (r & 3) + 8 * (r >> 2) + 4 * kh;
      float scq = __shfl(sc, qr);
      o0[r] *= scq;
      o1[r] *= scq;
    }
  }
  float p[16];
#pragma unroll
  for (int r = 0; r < 16; ++r) p[r] = __builtin_exp2f(s[r] * c1 - ml);
  float ps =
      (((p[0] + p[1]) + (p[2] + p[3])) + ((p[4] + p[5]) + (p[6] + p[7]))) +
      (((p[8] + p[9]) + (p[10] + p[11])) + ((p[12] + p[13]) + (p[14] + p[15])));
  ps += __shfl_xor(ps, 32);
  lsum += ps;
  // pack P (f32) -> bf16 pair words; build PV A-frags via half exchange
  union PW { unsigned u; bf16_t h[2]; };
#pragma unroll
  for (int ks = 0; ks < 2; ++ks) {
    const int rb = ks * 8;
    PW t0, t1, t2, t3;
    t0.h[0] = (bf16_t)p[rb + 0]; t0.h[1] = (bf16_t)p[rb + 1];
    t1.h[0] = (bf16_t)p[rb + 2]; t1.h[1] = (bf16_t)p[rb + 3];
    t2.h[0] = (bf16_t)p[rb + 4]; t2.h[1] = (bf16_t)p[rb + 5];
    t3.h[0] = (bf16_t)p[rb + 6]; t3.h[1] = (bf16_t)p[rb + 7];
    unsigned x0 = (unsigned)__shfl_xor((int)t0.u, 32);
    unsigned x1 = (unsigned)__shfl_xor((int)t1.u, 32);
    unsigned x2 = (unsigned)__shfl_xor((int)t2.u, 32);
    unsigned x3 = (unsigned)__shfl_xor((int)t3.u, 32);
    union { unsigned u[4]; bf16x8 v; } af;
    af.u[0] = lolane ? t0.u : x2;
    af.u[1] = lolane ? t1.u : x3;
    af.u[2] = lolane ? x0 : t2.u;
    af.u[3] = lolane ? x1 : t3.u;
    if (ks == 0) {
      o0 = mfma32(af.v, v00, o0);
      o1 = mfma32(af.v, v10, o1);
    } else {
      o0 = mfma32(af.v, v01, o0);
      o1 = mfma32(af.v, v11, o1);
    }
  }
}

// ---------------- flash attention: Q,K [bh][t][d], Vt [bh][d][t] ------------
__global__ __launch_bounds__(256) void k_attn(
    const bf16_t* __restrict__ Q, const bf16_t* __restrict__ K,
    const bf16_t* __restrict__ Vt, bf16_t* __restrict__ Ctx) {
  // bijective XCD swizzle: 512 blocks, 8 XCDs -> 4 heads per XCD (2MB < L2)
  const int lin = blockIdx.x + blockIdx.y * gridDim.x;
  const int logical = (lin & 7) * 64 + (lin >> 3);
  const int bh = logical >> 4, qblk = logical & 15;
  const int tid = threadIdx.x, lane = tid & 63, wid = tid >> 6;
  const int q0 = qblk * 128 + wid * 32;
  const int ql = lane & 31, kh = lane >> 5;
  const bool lolane = lane < 32;
  const bf16_t* Qp = Q + ((size_t)bh * T_ + q0 + ql) * HD_ + kh * 8;
  const bf16_t* Kp = K + ((size_t)bh * T_ + ql) * HD_ + kh * 8;
  const bf16_t* Vp = Vt + ((size_t)bh * HD_ + ql) * T_ + kh * 8;
  bf16x8 qf[4];
#pragma unroll
  for (int ds = 0; ds < 4; ++ds)
    qf[ds] = *reinterpret_cast<const bf16x8*>(Qp + ds * 16);
  bf16x8 kfA[4], kfB[4];
#pragma unroll
  for (int ds = 0; ds < 4; ++ds)
    kfA[ds] = *reinterpret_cast<const bf16x8*>(Kp + ds * 16);
  f32x16 o0, o1;
#pragma unroll
  for (int i = 0; i < 16; ++i) { o0[i] = 0.f; o1[i] = 0.f; }
  float ml = -1e30f, lsum = 0.f;
  for (int t = 0; t < T_; t += 64) {  // 2 tiles/iter, named K dbuf (reg-safe)
    attn_tile(t, Kp, Vp, qf, kfA, kfB, o0, o1, ml, lsum, kh, lolane);
    attn_tile(t + 32, Kp, Vp, qf, kfB, kfA, o0, o1, ml, lsum, kh, lolane);
  }
  float linv = 1.f / lsum;
  const int bb = bh >> 3, hh = bh & 7;
#pragma unroll
  for (int r = 0; r < 16; ++r) {
    const int qr = (r & 3) + 8 * (r >> 2) + 4 * kh;
    float li = __shfl(linv, qr);
    size_t base = ((size_t)(bb * T_ + q0 + qr)) * D_ + hh * HD_ + ql;
    Ctx[base] = (bf16_t)(o0[r] * li);
    Ctx[base + 32] = (bf16_t)(o1[r] * li);
  }
}

extern "C" void kernel_launch(void* const* d_in, const int* in_sizes, int n_in,
                              void* d_out, int out_size, void* d_ws,
                              size_t ws_size, hipStream_t stream) {
  const float* x    = (const float*)d_in[0];
  const float* Wqkv = (const float*)d_in[1];
  const float* bqkv = (const float*)d_in[2];
  const float* Wfc  = (const float*)d_in[3];
  const float* bfc  = (const float*)d_in[4];
  float* out = (float*)d_out;

  char* ws = (char*)d_ws;
  size_t off = 0;
  bf16_t* Wqt = (bf16_t*)(ws + off); off += (size_t)N3_ * D_ * 2;   // 1.5 MB
  bf16_t* Wft = (bf16_t*)(ws + off); off += (size_t)D_ * D_ * 2;    // 0.5 MB
  bf16_t* Qb  = (bf16_t*)(ws + off); off += (size_t)BT_ * D_ * 2;   // 8.4 MB
  bf16_t* Kb  = (bf16_t*)(ws + off); off += (size_t)BT_ * D_ * 2;
  bf16_t* Vb  = (bf16_t*)(ws + off); off += (size_t)BT_ * D_ * 2;
  bf16_t* Vtb = (bf16_t*)(ws + off); off += (size_t)BT_ * D_ * 2;
  bf16_t* Ctx = Vb;  // V is dead after k_vtrans; reuse for ctx

  k_tcast<<<dim3(N3_ / 64, D_ / 64), 256, 0, stream>>>(Wqkv, Wqt, D_, N3_);
  k_tcast<<<dim3(D_ / 64, D_ / 64), 256, 0, stream>>>(Wfc, Wft, D_, D_);
  k_gemm_qkv<<<dim3(BT_ / 128, N3_ / 128), 256, 0, stream>>>(x, Wqt, bqkv, Qb,
                                                             Kb, Vb);
  k_vtrans<<<dim3(T_ / 64, B_ * H_), 256, 0, stream>>>(Vb, Vtb);
  k_attn<<<dim3(T_ / 128, B_ * H_), 256, 0, stream>>>(Qb, Kb, Vtb, Ctx);
  k_gemm_fc<<<dim3(BT_ / 128, D_ / 128), 256, 0, stream>>>(Ctx, Wft, bfc, out);
}